// Round 6
// baseline (2608.940 us; speedup 1.0000x reference)
//
#include <hip/hip_runtime.h>
#include <math.h>

#define D 128
#define LN_EPS 1e-5f

#define NB_SHIFT 6                   // 64 nodes per bucket == GEMM row tile
#define BIN_EPT 16                   // edges per thread in hist/bin passes
#define BIN_CHUNK (BIN_EPT * 256)    // 4096 edges per block
#define MAXB 1600                    // >= NB (1563)
#define S 132                        // LDS acc row stride (floats): 2-way banks, free

typedef unsigned short ushort_t;
typedef unsigned int uint_t;
typedef __attribute__((ext_vector_type(8))) short bf16x8;
typedef __attribute__((ext_vector_type(8))) unsigned short u16x8;
typedef __attribute__((ext_vector_type(4))) float f32x4;

static __device__ __forceinline__ float bf2f(ushort_t u) {
    union { uint_t i; float f; } c; c.i = ((uint_t)u) << 16; return c.f;
}
static __device__ __forceinline__ ushort_t f2bf(float f) {
    union { float f; uint_t i; } c; c.f = f;
    uint_t u = c.i;
    uint_t r = (u + 0x7fffu + ((u >> 16) & 1u)) >> 16;   // RNE
    return (ushort_t)r;
}

// ---------------- casts ----------------
__global__ __launch_bounds__(256) void cast_f32_bf16(const float* __restrict__ in,
                                                     ushort_t* __restrict__ out, int n) {
    int i = (blockIdx.x * 256 + threadIdx.x) * 8;
    if (i + 8 > n) return;
    float4 a = *(const float4*)&in[i];
    float4 b = *(const float4*)&in[i + 4];
    u16x8 v;
    v[0] = f2bf(a.x); v[1] = f2bf(a.y); v[2] = f2bf(a.z); v[3] = f2bf(a.w);
    v[4] = f2bf(b.x); v[5] = f2bf(b.y); v[6] = f2bf(b.z); v[7] = f2bf(b.w);
    *(u16x8*)&out[i] = v;
}

// ---------------- graph build: bucket histogram -> scan -> binned pairs ------
__global__ __launch_bounds__(256) void bucket_hist_kernel(const int* __restrict__ ei, int E,
                                                          int* __restrict__ bcnt, int nb) {
    __shared__ int h[MAXB];
    const int tid = threadIdx.x;
    for (int i = tid; i < nb; i += 256) h[i] = 0;
    __syncthreads();
    int e0 = blockIdx.x * BIN_CHUNK;
    #pragma unroll
    for (int i = 0; i < BIN_EPT; ++i) {
        int e = e0 + i * 256 + tid;
        if (e < E) atomicAdd(&h[ei[E + e] >> NB_SHIFT], 1);
    }
    __syncthreads();
    for (int i = tid; i < nb; i += 256) {
        int c = h[i];
        if (c) atomicAdd(&bcnt[i], c);
    }
}

// single-block exclusive scan of bucket counts (nb <= 2048); bptr[nb]=E, bcur=copy
__global__ __launch_bounds__(1024) void scan_buckets_kernel(const int* __restrict__ bcnt,
                                                            int* __restrict__ bptr,
                                                            int* __restrict__ bcur, int nb) {
    __shared__ int wt[16];
    const int lane = threadIdx.x & 63;
    const int wid = threadIdx.x >> 6;
    int running = 0;
    for (int base = 0; base < nb; base += 1024) {
        int i = base + (int)threadIdx.x;
        int v = (i < nb) ? bcnt[i] : 0;
        int incl = v;
        #pragma unroll
        for (int off = 1; off < 64; off <<= 1) {
            int t = __shfl_up(incl, off, 64);
            if (lane >= off) incl += t;
        }
        if (lane == 63) wt[wid] = incl;
        __syncthreads();
        int prefix = running;
        for (int w = 0; w < wid; ++w) prefix += wt[w];
        if (i < nb) {
            int ex = prefix + incl - v;
            bptr[i] = ex;
            bcur[i] = ex;
        }
        int total = 0;
        for (int w = 0; w < 16; ++w) total += wt[w];
        __syncthreads();
        running += total;
    }
    if (threadIdx.x == 0) bptr[nb] = running;
}

// scatter (src,dst) pairs into per-bucket regions; LDS hist -> one reservation/bucket
__global__ __launch_bounds__(256) void bin_edges_kernel(const int* __restrict__ ei, int E,
                                                        int* __restrict__ bcur,
                                                        int2* __restrict__ pairs, int nb) {
    __shared__ int hist[MAXB];
    __shared__ int base[MAXB];
    const int tid = threadIdx.x;
    for (int i = tid; i < nb; i += 256) hist[i] = 0;
    __syncthreads();

    int e0 = blockIdx.x * BIN_CHUNK;
    int s_r[BIN_EPT], d_r[BIN_EPT], idx_r[BIN_EPT];
    #pragma unroll
    for (int i = 0; i < BIN_EPT; ++i) {
        int e = e0 + i * 256 + tid;
        if (e < E) {
            s_r[i] = ei[e];
            d_r[i] = ei[E + e];
            idx_r[i] = atomicAdd(&hist[d_r[i] >> NB_SHIFT], 1);
        }
    }
    __syncthreads();
    for (int i = tid; i < nb; i += 256) {
        int c = hist[i];
        base[i] = c ? atomicAdd(&bcur[i], c) : 0;
    }
    __syncthreads();
    #pragma unroll
    for (int i = 0; i < BIN_EPT; ++i) {
        int e = e0 + i * 256 + tid;
        if (e < E) {
            int pos = base[d_r[i] >> NB_SHIFT] + idx_r[i];
            pairs[pos] = make_int2(s_r[i], d_r[i]);
        }
    }
}

// ---------------- fused SAGE layer: LDS aggregation + MFMA GEMM + LN + SiLU ----
// Block = bucket b = nodes [b*64, b*64+64). Phase 1: gather neighbor rows,
// ds_add_f32 into 64x132 fp32 LDS acc + LDS degree counts. Phase 2: scale by
// 1/deg in place. Phase 3: MFMA (agg-half A-frags from LDS, hin-half from
// global; per-wave B frags hoisted in regs). Phase 4: LN+SiLU, store bf16.
__global__ __launch_bounds__(256) void sage_fused(
    const ushort_t* __restrict__ hprev,   // gather source AND hin (N x 128 bf16)
    const int2* __restrict__ pairs,
    const int* __restrict__ bptr,
    const ushort_t* __restrict__ Wl, const ushort_t* __restrict__ Wr,
    const float* __restrict__ bl, const float* __restrict__ br,
    const float* __restrict__ lng, const float* __restrict__ lnb,
    ushort_t* __restrict__ hout, int n) {
    __shared__ float acc_s[64 * S];       // 33.8 KB; reused as bf16 out-tile
    __shared__ int ldeg[64];
    __shared__ float part_s[64][4];
    __shared__ float part_s2[64][4];

    const int tid = threadIdx.x;
    const int w = tid >> 6;
    const int lane = tid & 63;
    const int quad = lane >> 4;
    const int l16 = lane & 15;
    const int b = blockIdx.x;
    const int n0 = b * 64;

    // hoist this wave's B fragments early (in flight during LDS zeroing)
    bf16x8 bfrag[8][2];
    #pragma unroll
    for (int c = 0; c < 8; ++c) {
        const ushort_t* __restrict__ W = (c < 4) ? Wl : Wr;
        const int kb = (c & 3) * 32;
        #pragma unroll
        for (int jl = 0; jl < 2; ++jl) {
            int j = (2 * w + jl) * 16 + l16;
            bfrag[c][jl] = *(const bf16x8*)&W[(size_t)j * D + kb + quad * 8];
        }
    }

    // phase 0: zero acc + deg
    for (int i = tid; i < 64 * S; i += 256) acc_s[i] = 0.0f;
    if (tid < 64) ldeg[tid] = 0;
    __syncthreads();

    // phase 1: edge aggregation. Wave handles 8 edges/iter (2 per 16-lane group).
    const int estart = bptr[b];
    const int eend = bptr[b + 1];
    const int eg = lane >> 4;   // 0..3
    for (int ebase = estart + w * 8; ebase < eend; ebase += 32) {
        int e0 = ebase + eg;
        int e1 = ebase + 4 + eg;
        bool v0 = e0 < eend, v1 = e1 < eend;
        int2 p0 = v0 ? pairs[e0] : make_int2(0, n0);
        int2 p1 = v1 ? pairs[e1] : make_int2(0, n0);
        u16x8 g0, g1;
        if (v0) g0 = *(const u16x8*)&hprev[(size_t)p0.x * D + l16 * 8];
        if (v1) g1 = *(const u16x8*)&hprev[(size_t)p1.x * D + l16 * 8];
        if (v0) {
            int dl = p0.y - n0;
            if (l16 == 0) atomicAdd(&ldeg[dl], 1);
            float* row = &acc_s[dl * S + l16 * 8];
            #pragma unroll
            for (int i = 0; i < 8; ++i) atomicAdd(&row[i], bf2f(g0[i]));
        }
        if (v1) {
            int dl = p1.y - n0;
            if (l16 == 0) atomicAdd(&ldeg[dl], 1);
            float* row = &acc_s[dl * S + l16 * 8];
            #pragma unroll
            for (int i = 0; i < 8; ++i) atomicAdd(&row[i], bf2f(g1[i]));
        }
    }
    __syncthreads();

    // phase 2: scale rows by 1/deg in place (4 threads per row, 32 cols each)
    {
        int row = tid >> 2;
        int c0 = (tid & 3) * 32;
        int dg = ldeg[row];
        float sc = (dg > 0) ? (1.0f / (float)dg) : 0.0f;
        float* rp = &acc_s[row * S + c0];
        #pragma unroll
        for (int k = 0; k < 32; k += 4) {
            f32x4 v = *(f32x4*)&rp[k];
            v.x *= sc; v.y *= sc; v.z *= sc; v.w *= sc;
            *(f32x4*)&rp[k] = v;
        }
    }
    __syncthreads();

    // phase 3: MFMA. rows of A clamped for hin-half loads
    int arow[4];
    #pragma unroll
    for (int rt = 0; rt < 4; ++rt) {
        int r = n0 + rt * 16 + l16;
        arow[rt] = (r < n) ? r : (n - 1);
    }

    f32x4 acc[4][2];
    #pragma unroll
    for (int rt = 0; rt < 4; ++rt)
        #pragma unroll
        for (int jl = 0; jl < 2; ++jl) acc[rt][jl] = (f32x4){0.f, 0.f, 0.f, 0.f};

    #pragma unroll
    for (int c = 0; c < 8; ++c) {
        const int kb = (c & 3) * 32;
        bf16x8 af[4];
        if (c < 4) {
            // agg-half: A frags from LDS fp32, convert to bf16
            #pragma unroll
            for (int rt = 0; rt < 4; ++rt) {
                const float* src = &acc_s[(rt * 16 + l16) * S + kb + quad * 8];
                f32x4 a0 = *(const f32x4*)src;
                f32x4 a1 = *(const f32x4*)(src + 4);
                bf16x8 t;
                t[0] = (short)f2bf(a0.x); t[1] = (short)f2bf(a0.y);
                t[2] = (short)f2bf(a0.z); t[3] = (short)f2bf(a0.w);
                t[4] = (short)f2bf(a1.x); t[5] = (short)f2bf(a1.y);
                t[6] = (short)f2bf(a1.z); t[7] = (short)f2bf(a1.w);
                af[rt] = t;
            }
        } else {
            #pragma unroll
            for (int rt = 0; rt < 4; ++rt)
                af[rt] = *(const bf16x8*)&hprev[(size_t)arow[rt] * D + kb + quad * 8];
        }
        #pragma unroll
        for (int rt = 0; rt < 4; ++rt)
            #pragma unroll
            for (int jl = 0; jl < 2; ++jl)
                acc[rt][jl] = __builtin_amdgcn_mfma_f32_16x16x32_bf16(af[rt], bfrag[c][jl],
                                                                      acc[rt][jl], 0, 0, 0);
    }

    // phase 4: bias + cross-wave LN + SiLU
    float bsum[2], g[2], bb[2];
    #pragma unroll
    for (int jl = 0; jl < 2; ++jl) {
        int j = (2 * w + jl) * 16 + l16;
        bsum[jl] = bl[j] + br[j];
        g[jl] = lng[j];
        bb[jl] = lnb[j];
    }
    #pragma unroll
    for (int rt = 0; rt < 4; ++rt) {
        #pragma unroll
        for (int r = 0; r < 4; ++r) {
            float v0 = acc[rt][0][r] + bsum[0];
            float v1 = acc[rt][1][r] + bsum[1];
            acc[rt][0][r] = v0;
            acc[rt][1][r] = v1;
            float s = v0 + v1;
            float s2 = v0 * v0 + v1 * v1;
            #pragma unroll
            for (int off = 1; off < 16; off <<= 1) {
                s += __shfl_xor(s, off, 64);
                s2 += __shfl_xor(s2, off, 64);
            }
            if (l16 == 0) {
                int row = rt * 16 + quad * 4 + r;
                part_s[row][w] = s;
                part_s2[row][w] = s2;
            }
        }
    }
    __syncthreads();   // also guards acc_s reuse as out-tile below

    ushort_t* tile = (ushort_t*)acc_s;   // 64 x 132 bf16 staging
    #pragma unroll
    for (int rt = 0; rt < 4; ++rt) {
        #pragma unroll
        for (int r = 0; r < 4; ++r) {
            int row = rt * 16 + quad * 4 + r;
            float s = part_s[row][0] + part_s[row][1] + part_s[row][2] + part_s[row][3];
            float s2 = part_s2[row][0] + part_s2[row][1] + part_s2[row][2] + part_s2[row][3];
            float mean = s * (1.0f / 128.0f);
            float var = s2 * (1.0f / 128.0f) - mean * mean;
            float rstd = rsqrtf(var + LN_EPS);
            #pragma unroll
            for (int jl = 0; jl < 2; ++jl) {
                float z = (acc[rt][jl][r] - mean) * rstd * g[jl] + bb[jl];
                float sv = z / (1.0f + expf(-z));
                tile[row * S + (2 * w + jl) * 16 + l16] = f2bf(sv);
            }
        }
    }
    __syncthreads();
    int row = tid >> 2, seg = tid & 3;
    int node = n0 + row;
    if (node < n) {
        #pragma unroll
        for (int k2 = 0; k2 < 4; ++k2) {
            u16x8 vv = *(const u16x8*)&tile[row * S + seg * 32 + k2 * 8];
            *(u16x8*)&hout[(size_t)node * D + seg * 32 + k2 * 8] = vv;
        }
    }
}

// ---------------- fused MLP head: MFMA + bias + ReLU + dot(w2) + b2 ----------
__global__ __launch_bounds__(256) void mlp_head_mfma(
    const ushort_t* __restrict__ hin, const ushort_t* __restrict__ W1,
    const float* __restrict__ b1, const float* __restrict__ w2,
    const float* __restrict__ b2, float* __restrict__ out, int n) {
    __shared__ float part[64][4];

    const int tid = threadIdx.x;
    const int w = tid >> 6;
    const int lane = tid & 63;
    const int quad = lane >> 4;
    const int l16 = lane & 15;
    const int n0 = blockIdx.x * 64;

    int arow[4];
    #pragma unroll
    for (int rt = 0; rt < 4; ++rt) {
        int r = n0 + rt * 16 + l16;
        arow[rt] = (r < n) ? r : (n - 1);
    }

    bf16x8 bfrag[4][2];
    #pragma unroll
    for (int c = 0; c < 4; ++c) {
        const int kb = c * 32;
        #pragma unroll
        for (int jl = 0; jl < 2; ++jl) {
            int j = (2 * w + jl) * 16 + l16;
            bfrag[c][jl] = *(const bf16x8*)&W1[(size_t)j * D + kb + quad * 8];
        }
    }

    f32x4 acc[4][2];
    #pragma unroll
    for (int rt = 0; rt < 4; ++rt)
        #pragma unroll
        for (int jl = 0; jl < 2; ++jl) acc[rt][jl] = (f32x4){0.f, 0.f, 0.f, 0.f};

    #pragma unroll
    for (int c = 0; c < 4; ++c) {
        const int kb = c * 32;
        bf16x8 af[4];
        #pragma unroll
        for (int rt = 0; rt < 4; ++rt)
            af[rt] = *(const bf16x8*)&hin[(size_t)arow[rt] * D + kb + quad * 8];
        #pragma unroll
        for (int rt = 0; rt < 4; ++rt)
            #pragma unroll
            for (int jl = 0; jl < 2; ++jl)
                acc[rt][jl] = __builtin_amdgcn_mfma_f32_16x16x32_bf16(af[rt], bfrag[c][jl],
                                                                      acc[rt][jl], 0, 0, 0);
    }

    float bias1[2], wv2[2];
    #pragma unroll
    for (int jl = 0; jl < 2; ++jl) {
        int j = (2 * w + jl) * 16 + l16;
        bias1[jl] = b1[j];
        wv2[jl] = w2[j];
    }
    #pragma unroll
    for (int rt = 0; rt < 4; ++rt) {
        #pragma unroll
        for (int r = 0; r < 4; ++r) {
            float p = fmaxf(acc[rt][0][r] + bias1[0], 0.0f) * wv2[0]
                    + fmaxf(acc[rt][1][r] + bias1[1], 0.0f) * wv2[1];
            #pragma unroll
            for (int off = 1; off < 16; off <<= 1) p += __shfl_xor(p, off, 64);
            if (l16 == 0) part[rt * 16 + quad * 4 + r][w] = p;
        }
    }
    __syncthreads();
    if (tid < 64) {
        int node = n0 + tid;
        if (node < n)
            out[node] = part[tid][0] + part[tid][1] + part[tid][2] + part[tid][3] + b2[0];
    }
}

// ---------------- launch ----------------
static inline size_t align_up(size_t v, size_t a) { return (v + a - 1) & ~(a - 1); }

extern "C" void kernel_launch(void* const* d_in, const int* in_sizes, int n_in,
                              void* d_out, int out_size, void* d_ws, size_t ws_size,
                              hipStream_t stream) {
    const float* x       = (const float*)d_in[0];
    const int*   ei      = (const int*)d_in[1];
    const float* lin_l_w = (const float*)d_in[2];
    const float* lin_l_b = (const float*)d_in[3];
    const float* lin_r_w = (const float*)d_in[4];
    const float* lin_r_b = (const float*)d_in[5];
    const float* ln_g    = (const float*)d_in[6];
    const float* ln_b    = (const float*)d_in[7];
    const float* mlp_w1  = (const float*)d_in[8];
    const float* mlp_b1  = (const float*)d_in[9];
    const float* mlp_w2  = (const float*)d_in[10];
    const float* mlp_b2  = (const float*)d_in[11];
    float* out = (float*)d_out;

    const int N = in_sizes[0] / D;   // 100000
    const int E = in_sizes[1] / 2;   // 1600000
    const int NB = (N + 63) >> NB_SHIFT;   // 1563

    // workspace layout
    char* w = (char*)d_ws;
    size_t off = 0;
    int* bcnt = (int*)(w + off);       off = align_up(off + sizeof(int) * (size_t)(NB + 1), 512);
    int* bptr = (int*)(w + off);       off = align_up(off + sizeof(int) * (size_t)(NB + 1), 512);
    int* bcur = (int*)(w + off);       off = align_up(off + sizeof(int) * (size_t)(NB + 1), 512);
    int2* pairs = (int2*)(w + off);    off = align_up(off + sizeof(int2) * (size_t)E, 512);
    ushort_t* x_bf = (ushort_t*)(w + off);   off = align_up(off + 2ull * N * D, 512);
    ushort_t* h1_bf = (ushort_t*)(w + off);  off = align_up(off + 2ull * N * D, 512);
    ushort_t* h2_bf = (ushort_t*)(w + off);  off = align_up(off + 2ull * N * D, 512);
    ushort_t* wl_bf = (ushort_t*)(w + off);  off = align_up(off + 2ull * 2 * D * D, 512);
    ushort_t* wr_bf = (ushort_t*)(w + off);  off = align_up(off + 2ull * 2 * D * D, 512);
    ushort_t* w1_bf = (ushort_t*)(w + off);  off = align_up(off + 2ull * D * D, 512);

    hipMemsetAsync(bcnt, 0, sizeof(int) * (size_t)(NB + 1), stream);

    // weight + input casts (bf16)
    cast_f32_bf16<<<(2 * D * D) / (8 * 256), 256, 0, stream>>>(lin_l_w, wl_bf, 2 * D * D);
    cast_f32_bf16<<<(2 * D * D) / (8 * 256), 256, 0, stream>>>(lin_r_w, wr_bf, 2 * D * D);
    cast_f32_bf16<<<(D * D + 8 * 256 - 1) / (8 * 256), 256, 0, stream>>>(mlp_w1, w1_bf, D * D);
    cast_f32_bf16<<<(N * D) / (8 * 256), 256, 0, stream>>>(x, x_bf, N * D);

    // graph build: bucket hist -> scan -> binned pairs (no CSR)
    const int bin_grid = (E + BIN_CHUNK - 1) / BIN_CHUNK;
    bucket_hist_kernel<<<bin_grid, 256, 0, stream>>>(ei, E, bcnt, NB);
    scan_buckets_kernel<<<1, 1024, 0, stream>>>(bcnt, bptr, bcur, NB);
    bin_edges_kernel<<<bin_grid, 256, 0, stream>>>(ei, E, bcur, pairs, NB);

    // layer 0
    sage_fused<<<NB, 256, 0, stream>>>(
        x_bf, pairs, bptr, wl_bf, wr_bf, lin_l_b, lin_r_b, ln_g, ln_b, h1_bf, N);
    // layer 1
    sage_fused<<<NB, 256, 0, stream>>>(
        h1_bf, pairs, bptr, wl_bf + D * D, wr_bf + D * D, lin_l_b + D, lin_r_b + D,
        ln_g + D, ln_b + D, h2_bf, N);
    // head
    mlp_head_mfma<<<NB, 256, 0, stream>>>(h2_bf, w1_bf, mlp_b1, mlp_w2, mlp_b2, out, N);
}

// Round 7
// 478.346 us; speedup vs baseline: 5.4541x; 5.4541x over previous
//
#include <hip/hip_runtime.h>
#include <math.h>

#define D 128
#define LN_EPS 1e-5f

#define SCAN_ITEMS 8
#define SCAN_BLOCK 256
#define SCAN_CHUNK (SCAN_ITEMS * SCAN_BLOCK)   // 2048 elements per block

#define NB_SHIFT 7                   // 128 nodes per bucket
#define BIN_EPT 16                   // edges per thread in bin pass
#define BIN_CHUNK (BIN_EPT * 256)    // 4096 edges per block

typedef unsigned short ushort_t;
typedef unsigned int uint_t;
typedef __attribute__((ext_vector_type(8))) short bf16x8;
typedef __attribute__((ext_vector_type(8))) unsigned short u16x8;
typedef __attribute__((ext_vector_type(4))) float f32x4;

static __device__ __forceinline__ float bf2f(ushort_t u) {
    union { uint_t i; float f; } c; c.i = ((uint_t)u) << 16; return c.f;
}
static __device__ __forceinline__ ushort_t f2bf(float f) {
    union { float f; uint_t i; } c; c.f = f;
    uint_t u = c.i;
    uint_t r = (u + 0x7fffu + ((u >> 16) & 1u)) >> 16;   // RNE
    return (ushort_t)r;
}

// ---------------- casts ----------------
__global__ __launch_bounds__(256) void cast_f32_bf16(const float* __restrict__ in,
                                                     ushort_t* __restrict__ out, int n) {
    int i = (blockIdx.x * 256 + threadIdx.x) * 8;
    if (i + 8 > n) return;
    float4 a = *(const float4*)&in[i];
    float4 b = *(const float4*)&in[i + 4];
    u16x8 v;
    v[0] = f2bf(a.x); v[1] = f2bf(a.y); v[2] = f2bf(a.z); v[3] = f2bf(a.w);
    v[4] = f2bf(b.x); v[5] = f2bf(b.y); v[6] = f2bf(b.z); v[7] = f2bf(b.w);
    *(u16x8*)&out[i] = v;
}

// ---------------- graph build ----------------
__global__ __launch_bounds__(256) void degree_kernel(const int* __restrict__ ei, int E,
                                                     int* __restrict__ deg) {
    int e = blockIdx.x * 256 + threadIdx.x;
    if (e >= E) return;
    atomicAdd(&deg[ei[E + e]], 1);
}

__global__ __launch_bounds__(SCAN_BLOCK) void block_sum_kernel(const int* __restrict__ deg,
                                                               int* __restrict__ blk_sums, int n) {
    int base = blockIdx.x * SCAN_CHUNK + threadIdx.x * SCAN_ITEMS;
    int s = 0;
    #pragma unroll
    for (int i = 0; i < SCAN_ITEMS; ++i) {
        int idx = base + i;
        if (idx < n) s += deg[idx];
    }
    #pragma unroll
    for (int off = 1; off < 64; off <<= 1) s += __shfl_xor(s, off, 64);
    __shared__ int ws[4];
    if ((threadIdx.x & 63) == 0) ws[threadIdx.x >> 6] = s;
    __syncthreads();
    if (threadIdx.x == 0) blk_sums[blockIdx.x] = ws[0] + ws[1] + ws[2] + ws[3];
}

__global__ __launch_bounds__(1024) void scan_sums_kernel(int* __restrict__ blk_sums, int nb,
                                                         int* __restrict__ row_ptr, int n) {
    __shared__ int wt[16];
    int i = threadIdx.x;
    int v = (i < nb) ? blk_sums[i] : 0;
    int lane = i & 63, wid = i >> 6;
    int incl = v;
    #pragma unroll
    for (int off = 1; off < 64; off <<= 1) {
        int t = __shfl_up(incl, off, 64);
        if (lane >= off) incl += t;
    }
    if (lane == 63) wt[wid] = incl;
    __syncthreads();
    int prefix = 0;
    for (int w = 0; w < wid; ++w) prefix += wt[w];
    if (i < nb) blk_sums[i] = prefix + incl - v;
    if (i == 0) {
        int tot = 0;
        for (int w = 0; w < 16; ++w) tot += wt[w];
        row_ptr[n] = tot;
    }
}

__global__ __launch_bounds__(SCAN_BLOCK) void scan_chunk_kernel(const int* __restrict__ deg,
                                                                const int* __restrict__ blk_offs,
                                                                int* __restrict__ row_ptr, int n) {
    int base = blockIdx.x * SCAN_CHUNK + threadIdx.x * SCAN_ITEMS;
    int vals[SCAN_ITEMS];
    int s = 0;
    #pragma unroll
    for (int i = 0; i < SCAN_ITEMS; ++i) {
        int idx = base + i;
        int v = (idx < n) ? deg[idx] : 0;
        vals[i] = s;
        s += v;
    }
    int lane = threadIdx.x & 63, wid = threadIdx.x >> 6;
    int incl = s;
    #pragma unroll
    for (int off = 1; off < 64; off <<= 1) {
        int t = __shfl_up(incl, off, 64);
        if (lane >= off) incl += t;
    }
    __shared__ int wt[4];
    if (lane == 63) wt[wid] = incl;
    __syncthreads();
    int prefix = 0;
    for (int w = 0; w < wid; ++w) prefix += wt[w];
    int texcl = prefix + incl - s + blk_offs[blockIdx.x];
    #pragma unroll
    for (int i = 0; i < SCAN_ITEMS; ++i) {
        int idx = base + i;
        if (idx < n) row_ptr[idx] = texcl + vals[i];
    }
}

__global__ __launch_bounds__(1024) void init_bcur_kernel(const int* __restrict__ row_ptr,
                                                         int* __restrict__ bcur, int nb, int n) {
    int b = threadIdx.x;
    if (b < nb) {
        int node = b << NB_SHIFT;
        if (node > n) node = n;
        bcur[b] = row_ptr[node];
    }
}

__global__ __launch_bounds__(256) void bin_edges_kernel(const int* __restrict__ ei, int E,
                                                        int* __restrict__ bcur,
                                                        int2* __restrict__ pairs, int nb) {
    __shared__ int hist[1024];
    __shared__ int base[1024];
    const int tid = threadIdx.x;
    for (int i = tid; i < nb; i += 256) hist[i] = 0;
    __syncthreads();

    int e0 = blockIdx.x * BIN_CHUNK;
    int s_r[BIN_EPT], d_r[BIN_EPT], idx_r[BIN_EPT];
    #pragma unroll
    for (int i = 0; i < BIN_EPT; ++i) {
        int e = e0 + i * 256 + tid;
        if (e < E) {
            s_r[i] = ei[e];
            d_r[i] = ei[E + e];
            idx_r[i] = atomicAdd(&hist[d_r[i] >> NB_SHIFT], 1);
        }
    }
    __syncthreads();
    for (int i = tid; i < nb; i += 256) {
        int c = hist[i];
        base[i] = c ? atomicAdd(&bcur[i], c) : 0;
    }
    __syncthreads();
    #pragma unroll
    for (int i = 0; i < BIN_EPT; ++i) {
        int e = e0 + i * 256 + tid;
        if (e < E) {
            int pos = base[d_r[i] >> NB_SHIFT] + idx_r[i];
            pairs[pos] = make_int2(s_r[i], d_r[i]);
        }
    }
}

__global__ __launch_bounds__(256) void csr_fill_binned(const int2* __restrict__ pairs, int E,
                                                       const int* __restrict__ row_ptr,
                                                       int* __restrict__ cursor,
                                                       int* __restrict__ csr_src) {
    int e = blockIdx.x * 256 + threadIdx.x;
    if (e >= E) return;
    int2 p = pairs[e];
    int pos = row_ptr[p.y] + atomicAdd(&cursor[p.y], 1);
    csr_src[pos] = p.x;
}

// ---------------- aggregation (bf16 gather, fp32 accum, bf16 out) ----------------
// 16 lanes per node; 8-wide edge unroll for memory-level parallelism.
__global__ __launch_bounds__(256) void aggregate_bf16(const ushort_t* __restrict__ h,
                                                      const int* __restrict__ row_ptr,
                                                      const int* __restrict__ csr_src,
                                                      ushort_t* __restrict__ agg, int n) {
    int node = blockIdx.x * 16 + (threadIdx.x >> 4);
    int lane = threadIdx.x & 15;
    if (node >= n) return;
    int s0 = row_ptr[node];
    int s1 = row_ptr[node + 1];
    float acc[8] = {0.f, 0.f, 0.f, 0.f, 0.f, 0.f, 0.f, 0.f};
    int e = s0;
    for (; e + 8 <= s1; e += 8) {
        int idx[8];
        #pragma unroll
        for (int j = 0; j < 8; ++j) idx[j] = csr_src[e + j];
        u16x8 v[8];
        #pragma unroll
        for (int j = 0; j < 8; ++j) v[j] = *(const u16x8*)&h[(size_t)idx[j] * D + lane * 8];
        #pragma unroll
        for (int i = 0; i < 8; ++i) {
            float s = 0.f;
            #pragma unroll
            for (int j = 0; j < 8; ++j) s += bf2f(v[j][i]);
            acc[i] += s;
        }
    }
    for (; e < s1; ++e) {
        int src = csr_src[e];
        u16x8 v = *(const u16x8*)&h[(size_t)src * D + lane * 8];
        #pragma unroll
        for (int i = 0; i < 8; ++i) acc[i] += bf2f(v[i]);
    }
    int dg = s1 - s0;
    float sc = (dg > 0) ? (1.0f / (float)dg) : 0.0f;
    u16x8 o;
    #pragma unroll
    for (int i = 0; i < 8; ++i) o[i] = f2bf(acc[i] * sc);
    *(u16x8*)&agg[(size_t)node * D + lane * 8] = o;
}

// ---------------- fused SAGE layer: LDS-staged A + MFMA + bias + LN + SiLU ----
// A-tile (64 rows x 256B of agg AND hin) staged to LDS in ONE latency exposure
// (8 coalesced 16B loads/thread), chunk-XOR swizzled (p = chunk ^ (row&7)) so
// K-loop ds_read_b128 frags are 2-way-bank (free). K-loop: 4 ds_reads + 2 B
// gathers (L2-hot weights) + 8 MFMAs per chunk — no serialized global latency.
__global__ __launch_bounds__(256) void sage_mfma(
    const ushort_t* __restrict__ agg, const ushort_t* __restrict__ hin,
    const ushort_t* __restrict__ Wl, const ushort_t* __restrict__ Wr,
    const float* __restrict__ bl, const float* __restrict__ br,
    const float* __restrict__ lng, const float* __restrict__ lnb,
    ushort_t* __restrict__ hout, int n) {
    __shared__ ushort_t stage[2 * 64 * 128];   // 32 KB; reused as bf16 out-tile
    __shared__ float part_s[64][4];
    __shared__ float part_s2[64][4];

    const int tid = threadIdx.x;
    const int w = tid >> 6;
    const int lane = tid & 63;
    const int quad = lane >> 4;
    const int l16 = lane & 15;
    const int n0 = blockIdx.x * 64;

    // stage A: half 0 = agg, half 1 = hin. granule g = row*16 + chunk (16B units)
    {
        #pragma unroll
        for (int i = 0; i < 4; ++i) {
            int g = i * 256 + tid;
            int row = g >> 4, ch = g & 15;
            int gr = n0 + row; if (gr >= n) gr = n - 1;
            u16x8 v = *(const u16x8*)&agg[(size_t)gr * D + ch * 8];
            *(u16x8*)&stage[row * 128 + (ch ^ (row & 7)) * 8] = v;
        }
        #pragma unroll
        for (int i = 0; i < 4; ++i) {
            int g = i * 256 + tid;
            int row = g >> 4, ch = g & 15;
            int gr = n0 + row; if (gr >= n) gr = n - 1;
            u16x8 v = *(const u16x8*)&hin[(size_t)gr * D + ch * 8];
            *(u16x8*)&stage[8192 + row * 128 + (ch ^ (row & 7)) * 8] = v;
        }
    }
    __syncthreads();

    f32x4 acc[4][2];
    #pragma unroll
    for (int rt = 0; rt < 4; ++rt)
        #pragma unroll
        for (int jl = 0; jl < 2; ++jl) acc[rt][jl] = (f32x4){0.f, 0.f, 0.f, 0.f};

    #pragma unroll
    for (int c = 0; c < 8; ++c) {
        const ushort_t* __restrict__ W = (c < 4) ? Wl : Wr;
        const int kb = (c & 3) * 32;
        const ushort_t* sbase = &stage[(c < 4) ? 0 : 8192];
        const int cl = (c & 3) * 4 + quad;            // logical 16B chunk in row
        bf16x8 bfr[2];
        #pragma unroll
        for (int jl = 0; jl < 2; ++jl) {
            int j = (2 * w + jl) * 16 + l16;
            bfr[jl] = *(const bf16x8*)&W[(size_t)j * D + kb + quad * 8];
        }
        bf16x8 af[4];
        #pragma unroll
        for (int rt = 0; rt < 4; ++rt) {
            int row = rt * 16 + l16;
            af[rt] = *(const bf16x8*)&sbase[row * 128 + ((cl ^ (l16 & 7)) * 8)];
        }
        #pragma unroll
        for (int rt = 0; rt < 4; ++rt)
            #pragma unroll
            for (int jl = 0; jl < 2; ++jl)
                acc[rt][jl] = __builtin_amdgcn_mfma_f32_16x16x32_bf16(af[rt], bfr[jl],
                                                                      acc[rt][jl], 0, 0, 0);
    }

    // epilogue: bias + cross-wave LN + SiLU
    float bsum[2], g[2], bb[2];
    #pragma unroll
    for (int jl = 0; jl < 2; ++jl) {
        int j = (2 * w + jl) * 16 + l16;
        bsum[jl] = bl[j] + br[j];
        g[jl] = lng[j];
        bb[jl] = lnb[j];
    }
    #pragma unroll
    for (int rt = 0; rt < 4; ++rt) {
        #pragma unroll
        for (int r = 0; r < 4; ++r) {
            float v0 = acc[rt][0][r] + bsum[0];
            float v1 = acc[rt][1][r] + bsum[1];
            acc[rt][0][r] = v0;
            acc[rt][1][r] = v1;
            float s = v0 + v1;
            float s2 = v0 * v0 + v1 * v1;
            #pragma unroll
            for (int off = 1; off < 16; off <<= 1) {
                s += __shfl_xor(s, off, 64);
                s2 += __shfl_xor(s2, off, 64);
            }
            if (l16 == 0) {
                int row = rt * 16 + quad * 4 + r;
                part_s[row][w] = s;
                part_s2[row][w] = s2;
            }
        }
    }
    __syncthreads();   // all ds_reads of stage done; safe to reuse as out-tile

    ushort_t* tile = stage;   // 64 x 132 bf16 staging (8448 <= 16384)
    #pragma unroll
    for (int rt = 0; rt < 4; ++rt) {
        #pragma unroll
        for (int r = 0; r < 4; ++r) {
            int row = rt * 16 + quad * 4 + r;
            float s = part_s[row][0] + part_s[row][1] + part_s[row][2] + part_s[row][3];
            float s2 = part_s2[row][0] + part_s2[row][1] + part_s2[row][2] + part_s2[row][3];
            float mean = s * (1.0f / 128.0f);
            float var = s2 * (1.0f / 128.0f) - mean * mean;
            float rstd = rsqrtf(var + LN_EPS);
            #pragma unroll
            for (int jl = 0; jl < 2; ++jl) {
                float z = (acc[rt][jl][r] - mean) * rstd * g[jl] + bb[jl];
                float sv = z / (1.0f + expf(-z));
                tile[row * 132 + (2 * w + jl) * 16 + l16] = f2bf(sv);
            }
        }
    }
    __syncthreads();
    int row = tid >> 2, seg = tid & 3;
    int node = n0 + row;
    if (node < n) {
        #pragma unroll
        for (int k2 = 0; k2 < 4; ++k2) {
            u16x8 vv = *(const u16x8*)&tile[row * 132 + seg * 32 + k2 * 8];
            *(u16x8*)&hout[(size_t)node * D + seg * 32 + k2 * 8] = vv;
        }
    }
}

// ---------------- fused MLP head: LDS-staged A + MFMA + ReLU + dot(w2) -------
__global__ __launch_bounds__(256) void mlp_head_mfma(
    const ushort_t* __restrict__ hin, const ushort_t* __restrict__ W1,
    const float* __restrict__ b1, const float* __restrict__ w2,
    const float* __restrict__ b2, float* __restrict__ out, int n) {
    __shared__ ushort_t stage[64 * 128];   // 16 KB
    __shared__ float part[64][4];

    const int tid = threadIdx.x;
    const int w = tid >> 6;
    const int lane = tid & 63;
    const int quad = lane >> 4;
    const int l16 = lane & 15;
    const int n0 = blockIdx.x * 64;

    #pragma unroll
    for (int i = 0; i < 4; ++i) {
        int g = i * 256 + tid;
        int row = g >> 4, ch = g & 15;
        int gr = n0 + row; if (gr >= n) gr = n - 1;
        u16x8 v = *(const u16x8*)&hin[(size_t)gr * D + ch * 8];
        *(u16x8*)&stage[row * 128 + (ch ^ (row & 7)) * 8] = v;
    }
    __syncthreads();

    f32x4 acc[4][2];
    #pragma unroll
    for (int rt = 0; rt < 4; ++rt)
        #pragma unroll
        for (int jl = 0; jl < 2; ++jl) acc[rt][jl] = (f32x4){0.f, 0.f, 0.f, 0.f};

    #pragma unroll
    for (int c = 0; c < 4; ++c) {
        const int kb = c * 32;
        const int cl = c * 4 + quad;
        bf16x8 bfr[2];
        #pragma unroll
        for (int jl = 0; jl < 2; ++jl) {
            int j = (2 * w + jl) * 16 + l16;
            bfr[jl] = *(const bf16x8*)&W1[(size_t)j * D + kb + quad * 8];
        }
        bf16x8 af[4];
        #pragma unroll
        for (int rt = 0; rt < 4; ++rt) {
            int row = rt * 16 + l16;
            af[rt] = *(const bf16x8*)&stage[row * 128 + ((cl ^ (l16 & 7)) * 8)];
        }
        #pragma unroll
        for (int rt = 0; rt < 4; ++rt)
            #pragma unroll
            for (int jl = 0; jl < 2; ++jl)
                acc[rt][jl] = __builtin_amdgcn_mfma_f32_16x16x32_bf16(af[rt], bfr[jl],
                                                                      acc[rt][jl], 0, 0, 0);
    }

    float bias1[2], wv2[2];
    #pragma unroll
    for (int jl = 0; jl < 2; ++jl) {
        int j = (2 * w + jl) * 16 + l16;
        bias1[jl] = b1[j];
        wv2[jl] = w2[j];
    }
    #pragma unroll
    for (int rt = 0; rt < 4; ++rt) {
        #pragma unroll
        for (int r = 0; r < 4; ++r) {
            float p = fmaxf(acc[rt][0][r] + bias1[0], 0.0f) * wv2[0]
                    + fmaxf(acc[rt][1][r] + bias1[1], 0.0f) * wv2[1];
            #pragma unroll
            for (int off = 1; off < 16; off <<= 1) p += __shfl_xor(p, off, 64);
            if (l16 == 0) part[rt * 16 + quad * 4 + r][w] = p;
        }
    }
    __syncthreads();
    if (tid < 64) {
        int node = n0 + tid;
        if (node < n)
            out[node] = part[tid][0] + part[tid][1] + part[tid][2] + part[tid][3] + b2[0];
    }
}

// ---------------- launch ----------------
static inline size_t align_up(size_t v, size_t a) { return (v + a - 1) & ~(a - 1); }

extern "C" void kernel_launch(void* const* d_in, const int* in_sizes, int n_in,
                              void* d_out, int out_size, void* d_ws, size_t ws_size,
                              hipStream_t stream) {
    const float* x       = (const float*)d_in[0];
    const int*   ei      = (const int*)d_in[1];
    const float* lin_l_w = (const float*)d_in[2];
    const float* lin_l_b = (const float*)d_in[3];
    const float* lin_r_w = (const float*)d_in[4];
    const float* lin_r_b = (const float*)d_in[5];
    const float* ln_g    = (const float*)d_in[6];
    const float* ln_b    = (const float*)d_in[7];
    const float* mlp_w1  = (const float*)d_in[8];
    const float* mlp_b1  = (const float*)d_in[9];
    const float* mlp_w2  = (const float*)d_in[10];
    const float* mlp_b2  = (const float*)d_in[11];
    float* out = (float*)d_out;

    const int N = in_sizes[0] / D;   // 100000
    const int E = in_sizes[1] / 2;   // 1600000
    const int NB = (N + (1 << NB_SHIFT) - 1) >> NB_SHIFT;   // 782

    // workspace layout
    char* w = (char*)d_ws;
    size_t off = 0;
    int* deg = (int*)(w + off);        off = align_up(off + sizeof(int) * (size_t)N, 512);
    int* row_ptr = (int*)(w + off);    off = align_up(off + sizeof(int) * (size_t)(N + 1), 512);
    int* cursor = (int*)(w + off);     off = align_up(off + sizeof(int) * (size_t)N, 512);
    int* blk_sums = (int*)(w + off);   off = align_up(off + sizeof(int) * 1024, 512);
    int* bcur = (int*)(w + off);       off = align_up(off + sizeof(int) * 1024, 512);
    int* csr_src = (int*)(w + off);    off = align_up(off + sizeof(int) * (size_t)E, 512);
    int2* pairs = (int2*)(w + off);    off = align_up(off + sizeof(int2) * (size_t)E, 512);
    ushort_t* x_bf = (ushort_t*)(w + off);   off = align_up(off + 2ull * N * D, 512);
    ushort_t* h1_bf = (ushort_t*)(w + off);  off = align_up(off + 2ull * N * D, 512);
    ushort_t* h2_bf = (ushort_t*)(w + off);  off = align_up(off + 2ull * N * D, 512);
    ushort_t* agg_bf = (ushort_t*)(w + off); off = align_up(off + 2ull * N * D, 512);
    ushort_t* wl_bf = (ushort_t*)(w + off);  off = align_up(off + 2ull * 2 * D * D, 512);
    ushort_t* wr_bf = (ushort_t*)(w + off);  off = align_up(off + 2ull * 2 * D * D, 512);
    ushort_t* w1_bf = (ushort_t*)(w + off);  off = align_up(off + 2ull * D * D, 512);

    hipMemsetAsync(deg, 0, sizeof(int) * (size_t)N, stream);
    hipMemsetAsync(cursor, 0, sizeof(int) * (size_t)N, stream);

    // weight + input casts (bf16)
    cast_f32_bf16<<<(2 * D * D) / (8 * 256), 256, 0, stream>>>(lin_l_w, wl_bf, 2 * D * D);
    cast_f32_bf16<<<(2 * D * D) / (8 * 256), 256, 0, stream>>>(lin_r_w, wr_bf, 2 * D * D);
    cast_f32_bf16<<<(D * D + 8 * 256 - 1) / (8 * 256), 256, 0, stream>>>(mlp_w1, w1_bf, D * D);
    cast_f32_bf16<<<(N * D) / (8 * 256), 256, 0, stream>>>(x, x_bf, N * D);

    // graph build
    degree_kernel<<<(E + 255) / 256, 256, 0, stream>>>(ei, E, deg);
    const int nb_scan = (N + SCAN_CHUNK - 1) / SCAN_CHUNK;
    block_sum_kernel<<<nb_scan, SCAN_BLOCK, 0, stream>>>(deg, blk_sums, N);
    scan_sums_kernel<<<1, 1024, 0, stream>>>(blk_sums, nb_scan, row_ptr, N);
    scan_chunk_kernel<<<nb_scan, SCAN_BLOCK, 0, stream>>>(deg, blk_sums, row_ptr, N);
    init_bcur_kernel<<<1, 1024, 0, stream>>>(row_ptr, bcur, NB, N);
    bin_edges_kernel<<<(E + BIN_CHUNK - 1) / BIN_CHUNK, 256, 0, stream>>>(ei, E, bcur, pairs, NB);
    csr_fill_binned<<<(E + 255) / 256, 256, 0, stream>>>(pairs, E, row_ptr, cursor, csr_src);

    const int gemm_grid = (N + 63) / 64;
    const int agg_grid = (N + 15) / 16;

    // layer 0
    aggregate_bf16<<<agg_grid, 256, 0, stream>>>(x_bf, row_ptr, csr_src, agg_bf, N);
    sage_mfma<<<gemm_grid, 256, 0, stream>>>(
        agg_bf, x_bf, wl_bf, wr_bf, lin_l_b, lin_r_b, ln_g, ln_b, h1_bf, N);
    // layer 1
    aggregate_bf16<<<agg_grid, 256, 0, stream>>>(h1_bf, row_ptr, csr_src, agg_bf, N);
    sage_mfma<<<gemm_grid, 256, 0, stream>>>(
        agg_bf, h1_bf, wl_bf + D * D, wr_bf + D * D, lin_l_b + D, lin_r_b + D,
        ln_g + D, ln_b + D, h2_bf, N);
    // head
    mlp_head_mfma<<<gemm_grid, 256, 0, stream>>>(h2_bf, w1_bf, mlp_b1, mlp_w2, mlp_b2, out, N);
}

// Round 8
// 390.473 us; speedup vs baseline: 6.6815x; 1.2250x over previous
//
#include <hip/hip_runtime.h>
#include <math.h>

#define D 128
#define LN_EPS 1e-5f

#define NB_SHIFT 7                   // 128 nodes per bucket
#define BIN_EPT 16                   // edges per thread in hist/bin passes
#define BIN_CHUNK (BIN_EPT * 256)    // 4096 edges per block
#define MAXB 800                     // >= NB (782)

typedef unsigned short ushort_t;
typedef unsigned int uint_t;
typedef __attribute__((ext_vector_type(8))) short bf16x8;
typedef __attribute__((ext_vector_type(8))) unsigned short u16x8;
typedef __attribute__((ext_vector_type(4))) float f32x4;

static __device__ __forceinline__ float bf2f(ushort_t u) {
    union { uint_t i; float f; } c; c.i = ((uint_t)u) << 16; return c.f;
}
static __device__ __forceinline__ ushort_t f2bf(float f) {
    union { float f; uint_t i; } c; c.f = f;
    uint_t u = c.i;
    uint_t r = (u + 0x7fffu + ((u >> 16) & 1u)) >> 16;   // RNE
    return (ushort_t)r;
}

// ---------------- casts ----------------
__global__ __launch_bounds__(256) void cast_f32_bf16(const float* __restrict__ in,
                                                     ushort_t* __restrict__ out, int n) {
    int i = (blockIdx.x * 256 + threadIdx.x) * 8;
    if (i + 8 > n) return;
    float4 a = *(const float4*)&in[i];
    float4 b = *(const float4*)&in[i + 4];
    u16x8 v;
    v[0] = f2bf(a.x); v[1] = f2bf(a.y); v[2] = f2bf(a.z); v[3] = f2bf(a.w);
    v[4] = f2bf(b.x); v[5] = f2bf(b.y); v[6] = f2bf(b.z); v[7] = f2bf(b.w);
    *(u16x8*)&out[i] = v;
}

// ---------------- graph build (bucket-local, no N-sized atomics) ----------------
// pass 1: per-block LDS histogram over buckets -> one global add per bucket/block
__global__ __launch_bounds__(256) void bucket_hist_kernel(const int* __restrict__ ei, int E,
                                                          int* __restrict__ bcnt, int nb) {
    __shared__ int h[MAXB];
    const int tid = threadIdx.x;
    for (int i = tid; i < nb; i += 256) h[i] = 0;
    __syncthreads();
    int e0 = blockIdx.x * BIN_CHUNK;
    #pragma unroll
    for (int i = 0; i < BIN_EPT; ++i) {
        int e = e0 + i * 256 + tid;
        if (e < E) atomicAdd(&h[ei[E + e] >> NB_SHIFT], 1);
    }
    __syncthreads();
    for (int i = tid; i < nb; i += 256) {
        int c = h[i];
        if (c) atomicAdd(&bcnt[i], c);
    }
}

// pass 2: single-block exclusive scan of bucket counts -> bptr (+bcur copy)
__global__ __launch_bounds__(1024) void scan_buckets_kernel(const int* __restrict__ bcnt,
                                                            int* __restrict__ bptr,
                                                            int* __restrict__ bcur, int nb) {
    __shared__ int wt[16];
    const int lane = threadIdx.x & 63;
    const int wid = threadIdx.x >> 6;
    int running = 0;
    for (int base = 0; base < nb; base += 1024) {
        int i = base + (int)threadIdx.x;
        int v = (i < nb) ? bcnt[i] : 0;
        int incl = v;
        #pragma unroll
        for (int off = 1; off < 64; off <<= 1) {
            int t = __shfl_up(incl, off, 64);
            if (lane >= off) incl += t;
        }
        if (lane == 63) wt[wid] = incl;
        __syncthreads();
        int prefix = running;
        for (int w = 0; w < wid; ++w) prefix += wt[w];
        if (i < nb) {
            int ex = prefix + incl - v;
            bptr[i] = ex;
            bcur[i] = ex;
        }
        int total = 0;
        for (int w = 0; w < 16; ++w) total += wt[w];
        __syncthreads();
        running += total;
    }
    if (threadIdx.x == 0) bptr[nb] = running;
}

// pass 3: scatter (src,dst) pairs into per-bucket regions (grouped writes)
__global__ __launch_bounds__(256) void bin_edges_kernel(const int* __restrict__ ei, int E,
                                                        int* __restrict__ bcur,
                                                        int2* __restrict__ pairs, int nb) {
    __shared__ int hist[MAXB];
    __shared__ int base[MAXB];
    const int tid = threadIdx.x;
    for (int i = tid; i < nb; i += 256) hist[i] = 0;
    __syncthreads();

    int e0 = blockIdx.x * BIN_CHUNK;
    int s_r[BIN_EPT], d_r[BIN_EPT], idx_r[BIN_EPT];
    #pragma unroll
    for (int i = 0; i < BIN_EPT; ++i) {
        int e = e0 + i * 256 + tid;
        if (e < E) {
            s_r[i] = ei[e];
            d_r[i] = ei[E + e];
            idx_r[i] = atomicAdd(&hist[d_r[i] >> NB_SHIFT], 1);
        }
    }
    __syncthreads();
    for (int i = tid; i < nb; i += 256) {
        int c = hist[i];
        base[i] = c ? atomicAdd(&bcur[i], c) : 0;
    }
    __syncthreads();
    #pragma unroll
    for (int i = 0; i < BIN_EPT; ++i) {
        int e = e0 + i * 256 + tid;
        if (e < E) {
            int pos = base[d_r[i] >> NB_SHIFT] + idx_r[i];
            pairs[pos] = make_int2(s_r[i], d_r[i]);
        }
    }
}

// pass 4: one block per bucket — LDS node-histogram + scan -> row_ptr, then
// scatter csr_src with LDS cursors (all writes land in the bucket's 8KB region)
__global__ __launch_bounds__(256) void bucket_csr_kernel(const int2* __restrict__ pairs,
                                                         const int* __restrict__ bptr,
                                                         int* __restrict__ row_ptr,
                                                         int* __restrict__ csr_src,
                                                         int nb, int n) {
    __shared__ int hist[128];
    __shared__ int cur[128];
    __shared__ int wtot[4];
    const int tid = threadIdx.x;
    const int b = blockIdx.x;
    const int e0 = bptr[b];
    const int e1 = bptr[b + 1];
    const int n0 = b << NB_SHIFT;

    if (tid < 128) hist[tid] = 0;
    __syncthreads();
    for (int e = e0 + tid; e < e1; e += 256)
        atomicAdd(&hist[pairs[e].y - n0], 1);
    __syncthreads();

    // exclusive scan of 128 counts (2 waves via shfl)
    int v = (tid < 128) ? hist[tid] : 0;
    int lane = tid & 63, wv = tid >> 6;
    int incl = v;
    #pragma unroll
    for (int off = 1; off < 64; off <<= 1) {
        int t = __shfl_up(incl, off, 64);
        if (lane >= off) incl += t;
    }
    if (lane == 63) wtot[wv] = incl;
    __syncthreads();
    if (tid < 128) {
        int excl = incl - v + ((wv == 1) ? wtot[0] : 0);
        cur[tid] = excl;
        int node = n0 + tid;
        if (node < n) row_ptr[node] = e0 + excl;
    }
    if (b == nb - 1 && tid == 0) row_ptr[n] = e1;
    __syncthreads();

    for (int e = e0 + tid; e < e1; e += 256) {
        int2 p = pairs[e];
        int pos = e0 + atomicAdd(&cur[p.y - n0], 1);
        csr_src[pos] = p.x;
    }
}

// ---------------- aggregation (bf16 gather, fp32 accum, bf16 out) ----------------
// 16 lanes per node; 8-wide edge unroll for memory-level parallelism.
__global__ __launch_bounds__(256) void aggregate_bf16(const ushort_t* __restrict__ h,
                                                      const int* __restrict__ row_ptr,
                                                      const int* __restrict__ csr_src,
                                                      ushort_t* __restrict__ agg, int n) {
    int node = blockIdx.x * 16 + (threadIdx.x >> 4);
    int lane = threadIdx.x & 15;
    if (node >= n) return;
    int s0 = row_ptr[node];
    int s1 = row_ptr[node + 1];
    float acc[8] = {0.f, 0.f, 0.f, 0.f, 0.f, 0.f, 0.f, 0.f};
    int e = s0;
    for (; e + 8 <= s1; e += 8) {
        int idx[8];
        #pragma unroll
        for (int j = 0; j < 8; ++j) idx[j] = csr_src[e + j];
        u16x8 v[8];
        #pragma unroll
        for (int j = 0; j < 8; ++j) v[j] = *(const u16x8*)&h[(size_t)idx[j] * D + lane * 8];
        #pragma unroll
        for (int i = 0; i < 8; ++i) {
            float s = 0.f;
            #pragma unroll
            for (int j = 0; j < 8; ++j) s += bf2f(v[j][i]);
            acc[i] += s;
        }
    }
    for (; e < s1; ++e) {
        int src = csr_src[e];
        u16x8 v = *(const u16x8*)&h[(size_t)src * D + lane * 8];
        #pragma unroll
        for (int i = 0; i < 8; ++i) acc[i] += bf2f(v[i]);
    }
    int dg = s1 - s0;
    float sc = (dg > 0) ? (1.0f / (float)dg) : 0.0f;
    u16x8 o;
    #pragma unroll
    for (int i = 0; i < 8; ++i) o[i] = f2bf(acc[i] * sc);
    *(u16x8*)&agg[(size_t)node * D + lane * 8] = o;
}

// ---------------- fused SAGE layer: LDS-staged A + MFMA + bias + LN + SiLU ----
__global__ __launch_bounds__(256) void sage_mfma(
    const ushort_t* __restrict__ agg, const ushort_t* __restrict__ hin,
    const ushort_t* __restrict__ Wl, const ushort_t* __restrict__ Wr,
    const float* __restrict__ bl, const float* __restrict__ br,
    const float* __restrict__ lng, const float* __restrict__ lnb,
    ushort_t* __restrict__ hout, int n) {
    __shared__ ushort_t stage[2 * 64 * 128];   // 32 KB; reused as bf16 out-tile
    __shared__ float part_s[64][4];
    __shared__ float part_s2[64][4];

    const int tid = threadIdx.x;
    const int w = tid >> 6;
    const int lane = tid & 63;
    const int quad = lane >> 4;
    const int l16 = lane & 15;
    const int n0 = blockIdx.x * 64;

    // stage A: half 0 = agg, half 1 = hin; chunk-XOR swizzle (p = ch ^ (row&7))
    {
        #pragma unroll
        for (int i = 0; i < 4; ++i) {
            int g = i * 256 + tid;
            int row = g >> 4, ch = g & 15;
            int gr = n0 + row; if (gr >= n) gr = n - 1;
            u16x8 v = *(const u16x8*)&agg[(size_t)gr * D + ch * 8];
            *(u16x8*)&stage[row * 128 + (ch ^ (row & 7)) * 8] = v;
        }
        #pragma unroll
        for (int i = 0; i < 4; ++i) {
            int g = i * 256 + tid;
            int row = g >> 4, ch = g & 15;
            int gr = n0 + row; if (gr >= n) gr = n - 1;
            u16x8 v = *(const u16x8*)&hin[(size_t)gr * D + ch * 8];
            *(u16x8*)&stage[8192 + row * 128 + (ch ^ (row & 7)) * 8] = v;
        }
    }
    __syncthreads();

    f32x4 acc[4][2];
    #pragma unroll
    for (int rt = 0; rt < 4; ++rt)
        #pragma unroll
        for (int jl = 0; jl < 2; ++jl) acc[rt][jl] = (f32x4){0.f, 0.f, 0.f, 0.f};

    #pragma unroll
    for (int c = 0; c < 8; ++c) {
        const ushort_t* __restrict__ W = (c < 4) ? Wl : Wr;
        const int kb = (c & 3) * 32;
        const ushort_t* sbase = &stage[(c < 4) ? 0 : 8192];
        const int cl = (c & 3) * 4 + quad;
        bf16x8 bfr[2];
        #pragma unroll
        for (int jl = 0; jl < 2; ++jl) {
            int j = (2 * w + jl) * 16 + l16;
            bfr[jl] = *(const bf16x8*)&W[(size_t)j * D + kb + quad * 8];
        }
        bf16x8 af[4];
        #pragma unroll
        for (int rt = 0; rt < 4; ++rt) {
            int row = rt * 16 + l16;
            af[rt] = *(const bf16x8*)&sbase[row * 128 + ((cl ^ (l16 & 7)) * 8)];
        }
        #pragma unroll
        for (int rt = 0; rt < 4; ++rt)
            #pragma unroll
            for (int jl = 0; jl < 2; ++jl)
                acc[rt][jl] = __builtin_amdgcn_mfma_f32_16x16x32_bf16(af[rt], bfr[jl],
                                                                      acc[rt][jl], 0, 0, 0);
    }

    float bsum[2], g[2], bb[2];
    #pragma unroll
    for (int jl = 0; jl < 2; ++jl) {
        int j = (2 * w + jl) * 16 + l16;
        bsum[jl] = bl[j] + br[j];
        g[jl] = lng[j];
        bb[jl] = lnb[j];
    }
    #pragma unroll
    for (int rt = 0; rt < 4; ++rt) {
        #pragma unroll
        for (int r = 0; r < 4; ++r) {
            float v0 = acc[rt][0][r] + bsum[0];
            float v1 = acc[rt][1][r] + bsum[1];
            acc[rt][0][r] = v0;
            acc[rt][1][r] = v1;
            float s = v0 + v1;
            float s2 = v0 * v0 + v1 * v1;
            #pragma unroll
            for (int off = 1; off < 16; off <<= 1) {
                s += __shfl_xor(s, off, 64);
                s2 += __shfl_xor(s2, off, 64);
            }
            if (l16 == 0) {
                int row = rt * 16 + quad * 4 + r;
                part_s[row][w] = s;
                part_s2[row][w] = s2;
            }
        }
    }
    __syncthreads();

    ushort_t* tile = stage;
    #pragma unroll
    for (int rt = 0; rt < 4; ++rt) {
        #pragma unroll
        for (int r = 0; r < 4; ++r) {
            int row = rt * 16 + quad * 4 + r;
            float s = part_s[row][0] + part_s[row][1] + part_s[row][2] + part_s[row][3];
            float s2 = part_s2[row][0] + part_s2[row][1] + part_s2[row][2] + part_s2[row][3];
            float mean = s * (1.0f / 128.0f);
            float var = s2 * (1.0f / 128.0f) - mean * mean;
            float rstd = rsqrtf(var + LN_EPS);
            #pragma unroll
            for (int jl = 0; jl < 2; ++jl) {
                float z = (acc[rt][jl][r] - mean) * rstd * g[jl] + bb[jl];
                float sv = z / (1.0f + expf(-z));
                tile[row * 132 + (2 * w + jl) * 16 + l16] = f2bf(sv);
            }
        }
    }
    __syncthreads();
    int row = tid >> 2, seg = tid & 3;
    int node = n0 + row;
    if (node < n) {
        #pragma unroll
        for (int k2 = 0; k2 < 4; ++k2) {
            u16x8 vv = *(const u16x8*)&tile[row * 132 + seg * 32 + k2 * 8];
            *(u16x8*)&hout[(size_t)node * D + seg * 32 + k2 * 8] = vv;
        }
    }
}

// ---------------- fused MLP head: LDS-staged A + MFMA + ReLU + dot(w2) -------
__global__ __launch_bounds__(256) void mlp_head_mfma(
    const ushort_t* __restrict__ hin, const ushort_t* __restrict__ W1,
    const float* __restrict__ b1, const float* __restrict__ w2,
    const float* __restrict__ b2, float* __restrict__ out, int n) {
    __shared__ ushort_t stage[64 * 128];
    __shared__ float part[64][4];

    const int tid = threadIdx.x;
    const int w = tid >> 6;
    const int lane = tid & 63;
    const int quad = lane >> 4;
    const int l16 = lane & 15;
    const int n0 = blockIdx.x * 64;

    #pragma unroll
    for (int i = 0; i < 4; ++i) {
        int g = i * 256 + tid;
        int row = g >> 4, ch = g & 15;
        int gr = n0 + row; if (gr >= n) gr = n - 1;
        u16x8 v = *(const u16x8*)&hin[(size_t)gr * D + ch * 8];
        *(u16x8*)&stage[row * 128 + (ch ^ (row & 7)) * 8] = v;
    }
    __syncthreads();

    f32x4 acc[4][2];
    #pragma unroll
    for (int rt = 0; rt < 4; ++rt)
        #pragma unroll
        for (int jl = 0; jl < 2; ++jl) acc[rt][jl] = (f32x4){0.f, 0.f, 0.f, 0.f};

    #pragma unroll
    for (int c = 0; c < 4; ++c) {
        const int kb = c * 32;
        const int cl = c * 4 + quad;
        bf16x8 bfr[2];
        #pragma unroll
        for (int jl = 0; jl < 2; ++jl) {
            int j = (2 * w + jl) * 16 + l16;
            bfr[jl] = *(const bf16x8*)&W1[(size_t)j * D + kb + quad * 8];
        }
        bf16x8 af[4];
        #pragma unroll
        for (int rt = 0; rt < 4; ++rt) {
            int row = rt * 16 + l16;
            af[rt] = *(const bf16x8*)&stage[row * 128 + ((cl ^ (l16 & 7)) * 8)];
        }
        #pragma unroll
        for (int rt = 0; rt < 4; ++rt)
            #pragma unroll
            for (int jl = 0; jl < 2; ++jl)
                acc[rt][jl] = __builtin_amdgcn_mfma_f32_16x16x32_bf16(af[rt], bfr[jl],
                                                                      acc[rt][jl], 0, 0, 0);
    }

    float bias1[2], wv2[2];
    #pragma unroll
    for (int jl = 0; jl < 2; ++jl) {
        int j = (2 * w + jl) * 16 + l16;
        bias1[jl] = b1[j];
        wv2[jl] = w2[j];
    }
    #pragma unroll
    for (int rt = 0; rt < 4; ++rt) {
        #pragma unroll
        for (int r = 0; r < 4; ++r) {
            float p = fmaxf(acc[rt][0][r] + bias1[0], 0.0f) * wv2[0]
                    + fmaxf(acc[rt][1][r] + bias1[1], 0.0f) * wv2[1];
            #pragma unroll
            for (int off = 1; off < 16; off <<= 1) p += __shfl_xor(p, off, 64);
            if (l16 == 0) part[rt * 16 + quad * 4 + r][w] = p;
        }
    }
    __syncthreads();
    if (tid < 64) {
        int node = n0 + tid;
        if (node < n)
            out[node] = part[tid][0] + part[tid][1] + part[tid][2] + part[tid][3] + b2[0];
    }
}

// ---------------- launch ----------------
static inline size_t align_up(size_t v, size_t a) { return (v + a - 1) & ~(a - 1); }

extern "C" void kernel_launch(void* const* d_in, const int* in_sizes, int n_in,
                              void* d_out, int out_size, void* d_ws, size_t ws_size,
                              hipStream_t stream) {
    const float* x       = (const float*)d_in[0];
    const int*   ei      = (const int*)d_in[1];
    const float* lin_l_w = (const float*)d_in[2];
    const float* lin_l_b = (const float*)d_in[3];
    const float* lin_r_w = (const float*)d_in[4];
    const float* lin_r_b = (const float*)d_in[5];
    const float* ln_g    = (const float*)d_in[6];
    const float* ln_b    = (const float*)d_in[7];
    const float* mlp_w1  = (const float*)d_in[8];
    const float* mlp_b1  = (const float*)d_in[9];
    const float* mlp_w2  = (const float*)d_in[10];
    const float* mlp_b2  = (const float*)d_in[11];
    float* out = (float*)d_out;

    const int N = in_sizes[0] / D;   // 100000
    const int E = in_sizes[1] / 2;   // 1600000
    const int NB = (N + (1 << NB_SHIFT) - 1) >> NB_SHIFT;   // 782

    // workspace layout
    char* w = (char*)d_ws;
    size_t off = 0;
    int* bcnt = (int*)(w + off);       off = align_up(off + sizeof(int) * (size_t)(NB + 1), 512);
    int* bptr = (int*)(w + off);       off = align_up(off + sizeof(int) * (size_t)(NB + 1), 512);
    int* bcur = (int*)(w + off);       off = align_up(off + sizeof(int) * (size_t)(NB + 1), 512);
    int* row_ptr = (int*)(w + off);    off = align_up(off + sizeof(int) * (size_t)(N + 1), 512);
    int* csr_src = (int*)(w + off);    off = align_up(off + sizeof(int) * (size_t)E, 512);
    int2* pairs = (int2*)(w + off);    off = align_up(off + sizeof(int2) * (size_t)E, 512);
    ushort_t* x_bf = (ushort_t*)(w + off);   off = align_up(off + 2ull * N * D, 512);
    ushort_t* h1_bf = (ushort_t*)(w + off);  off = align_up(off + 2ull * N * D, 512);
    ushort_t* h2_bf = (ushort_t*)(w + off);  off = align_up(off + 2ull * N * D, 512);
    ushort_t* agg_bf = (ushort_t*)(w + off); off = align_up(off + 2ull * N * D, 512);
    ushort_t* wl_bf = (ushort_t*)(w + off);  off = align_up(off + 2ull * 2 * D * D, 512);
    ushort_t* wr_bf = (ushort_t*)(w + off);  off = align_up(off + 2ull * 2 * D * D, 512);
    ushort_t* w1_bf = (ushort_t*)(w + off);  off = align_up(off + 2ull * D * D, 512);

    hipMemsetAsync(bcnt, 0, sizeof(int) * (size_t)(NB + 1), stream);

    // weight + input casts (bf16)
    cast_f32_bf16<<<(2 * D * D) / (8 * 256), 256, 0, stream>>>(lin_l_w, wl_bf, 2 * D * D);
    cast_f32_bf16<<<(2 * D * D) / (8 * 256), 256, 0, stream>>>(lin_r_w, wr_bf, 2 * D * D);
    cast_f32_bf16<<<(D * D + 8 * 256 - 1) / (8 * 256), 256, 0, stream>>>(mlp_w1, w1_bf, D * D);
    cast_f32_bf16<<<(N * D) / (8 * 256), 256, 0, stream>>>(x, x_bf, N * D);

    // graph build: bucket hist -> scan -> binned pairs -> bucket-local CSR
    const int bin_grid = (E + BIN_CHUNK - 1) / BIN_CHUNK;
    bucket_hist_kernel<<<bin_grid, 256, 0, stream>>>(ei, E, bcnt, NB);
    scan_buckets_kernel<<<1, 1024, 0, stream>>>(bcnt, bptr, bcur, NB);
    bin_edges_kernel<<<bin_grid, 256, 0, stream>>>(ei, E, bcur, pairs, NB);
    bucket_csr_kernel<<<NB, 256, 0, stream>>>(pairs, bptr, row_ptr, csr_src, NB, N);

    const int gemm_grid = (N + 63) / 64;
    const int agg_grid = (N + 15) / 16;

    // layer 0
    aggregate_bf16<<<agg_grid, 256, 0, stream>>>(x_bf, row_ptr, csr_src, agg_bf, N);
    sage_mfma<<<gemm_grid, 256, 0, stream>>>(
        agg_bf, x_bf, wl_bf, wr_bf, lin_l_b, lin_r_b, ln_g, ln_b, h1_bf, N);
    // layer 1
    aggregate_bf16<<<agg_grid, 256, 0, stream>>>(h1_bf, row_ptr, csr_src, agg_bf, N);
    sage_mfma<<<gemm_grid, 256, 0, stream>>>(
        agg_bf, h1_bf, wl_bf + D * D, wr_bf + D * D, lin_l_b + D, lin_r_b + D,
        ln_g + D, ln_b + D, h2_bf, N);
    // head
    mlp_head_mfma<<<gemm_grid, 256, 0, stream>>>(h2_bf, w1_bf, mlp_b1, mlp_w2, mlp_b2, out, N);
}

// Round 9
// 380.044 us; speedup vs baseline: 6.8648x; 1.0274x over previous
//
#include <hip/hip_runtime.h>
#include <math.h>

#define D 128
#define LN_EPS 1e-5f

#define NB_SHIFT 7                   // 128 nodes per bucket
#define BIN_EPT 16                   // edges per thread in hist/bin passes
#define BIN_CHUNK (BIN_EPT * 256)    // 4096 edges per block
#define MAXB 800                     // >= NB (782)
#define SRC_BITS 25                  // pack: (dloc << 25) | src  (src < 2^25)

typedef unsigned short ushort_t;
typedef unsigned int uint_t;
typedef __attribute__((ext_vector_type(8))) short bf16x8;
typedef __attribute__((ext_vector_type(8))) unsigned short u16x8;
typedef __attribute__((ext_vector_type(4))) float f32x4;

static __device__ __forceinline__ float bf2f(ushort_t u) {
    union { uint_t i; float f; } c; c.i = ((uint_t)u) << 16; return c.f;
}
static __device__ __forceinline__ ushort_t f2bf(float f) {
    union { float f; uint_t i; } c; c.f = f;
    uint_t u = c.i;
    uint_t r = (u + 0x7fffu + ((u >> 16) & 1u)) >> 16;   // RNE
    return (ushort_t)r;
}

// ---------------- casts ----------------
__global__ __launch_bounds__(256) void cast_f32_bf16(const float* __restrict__ in,
                                                     ushort_t* __restrict__ out, int n) {
    int i = (blockIdx.x * 256 + threadIdx.x) * 8;
    if (i + 8 > n) return;
    float4 a = *(const float4*)&in[i];
    float4 b = *(const float4*)&in[i + 4];
    u16x8 v;
    v[0] = f2bf(a.x); v[1] = f2bf(a.y); v[2] = f2bf(a.z); v[3] = f2bf(a.w);
    v[4] = f2bf(b.x); v[5] = f2bf(b.y); v[6] = f2bf(b.z); v[7] = f2bf(b.w);
    *(u16x8*)&out[i] = v;
}

// ---------------- graph build (bucket-local) ----------------
__global__ __launch_bounds__(256) void bucket_hist_kernel(const int* __restrict__ ei, int E,
                                                          int* __restrict__ bcnt, int nb) {
    __shared__ int h[MAXB];
    const int tid = threadIdx.x;
    for (int i = tid; i < nb; i += 256) h[i] = 0;
    __syncthreads();
    int e0 = blockIdx.x * BIN_CHUNK;
    #pragma unroll
    for (int i = 0; i < BIN_EPT; ++i) {
        int e = e0 + i * 256 + tid;
        if (e < E) atomicAdd(&h[ei[E + e] >> NB_SHIFT], 1);
    }
    __syncthreads();
    for (int i = tid; i < nb; i += 256) {
        int c = h[i];
        if (c) atomicAdd(&bcnt[i], c);
    }
}

__global__ __launch_bounds__(1024) void scan_buckets_kernel(const int* __restrict__ bcnt,
                                                            int* __restrict__ bptr,
                                                            int* __restrict__ bcur, int nb) {
    __shared__ int wt[16];
    const int lane = threadIdx.x & 63;
    const int wid = threadIdx.x >> 6;
    int running = 0;
    for (int base = 0; base < nb; base += 1024) {
        int i = base + (int)threadIdx.x;
        int v = (i < nb) ? bcnt[i] : 0;
        int incl = v;
        #pragma unroll
        for (int off = 1; off < 64; off <<= 1) {
            int t = __shfl_up(incl, off, 64);
            if (lane >= off) incl += t;
        }
        if (lane == 63) wt[wid] = incl;
        __syncthreads();
        int prefix = running;
        for (int w = 0; w < wid; ++w) prefix += wt[w];
        if (i < nb) {
            int ex = prefix + incl - v;
            bptr[i] = ex;
            bcur[i] = ex;
        }
        int total = 0;
        for (int w = 0; w < 16; ++w) total += wt[w];
        __syncthreads();
        running += total;
    }
    if (threadIdx.x == 0) bptr[nb] = running;
}

// scatter packed (dloc<<25 | src) into per-bucket regions
__global__ __launch_bounds__(256) void bin_edges_kernel(const int* __restrict__ ei, int E,
                                                        int* __restrict__ bcur,
                                                        uint_t* __restrict__ pairs, int nb) {
    __shared__ int hist[MAXB];
    __shared__ int base[MAXB];
    const int tid = threadIdx.x;
    for (int i = tid; i < nb; i += 256) hist[i] = 0;
    __syncthreads();

    int e0 = blockIdx.x * BIN_CHUNK;
    int s_r[BIN_EPT], d_r[BIN_EPT], idx_r[BIN_EPT];
    #pragma unroll
    for (int i = 0; i < BIN_EPT; ++i) {
        int e = e0 + i * 256 + tid;
        if (e < E) {
            s_r[i] = ei[e];
            d_r[i] = ei[E + e];
            idx_r[i] = atomicAdd(&hist[d_r[i] >> NB_SHIFT], 1);
        }
    }
    __syncthreads();
    for (int i = tid; i < nb; i += 256) {
        int c = hist[i];
        base[i] = c ? atomicAdd(&bcur[i], c) : 0;
    }
    __syncthreads();
    #pragma unroll
    for (int i = 0; i < BIN_EPT; ++i) {
        int e = e0 + i * 256 + tid;
        if (e < E) {
            int pos = base[d_r[i] >> NB_SHIFT] + idx_r[i];
            pairs[pos] = ((uint_t)(d_r[i] & 127) << SRC_BITS) | (uint_t)s_r[i];
        }
    }
}

// one block per bucket: LDS node-hist + scan -> row_ptr; scatter csr_src locally
__global__ __launch_bounds__(256) void bucket_csr_kernel(const uint_t* __restrict__ pairs,
                                                         const int* __restrict__ bptr,
                                                         int* __restrict__ row_ptr,
                                                         int* __restrict__ csr_src,
                                                         int nb, int n) {
    __shared__ int hist[128];
    __shared__ int cur[128];
    __shared__ int wtot[4];
    const int tid = threadIdx.x;
    const int b = blockIdx.x;
    const int e0 = bptr[b];
    const int e1 = bptr[b + 1];
    const int n0 = b << NB_SHIFT;

    if (tid < 128) hist[tid] = 0;
    __syncthreads();
    for (int e = e0 + tid; e < e1; e += 256)
        atomicAdd(&hist[pairs[e] >> SRC_BITS], 1);
    __syncthreads();

    int v = (tid < 128) ? hist[tid] : 0;
    int lane = tid & 63, wv = tid >> 6;
    int incl = v;
    #pragma unroll
    for (int off = 1; off < 64; off <<= 1) {
        int t = __shfl_up(incl, off, 64);
        if (lane >= off) incl += t;
    }
    if (lane == 63) wtot[wv] = incl;
    __syncthreads();
    if (tid < 128) {
        int excl = incl - v + ((wv == 1) ? wtot[0] : 0);
        cur[tid] = excl;
        int node = n0 + tid;
        if (node < n) row_ptr[node] = e0 + excl;
    }
    if (b == nb - 1 && tid == 0) row_ptr[n] = e1;
    __syncthreads();

    for (int e = e0 + tid; e < e1; e += 256) {
        uint_t p = pairs[e];
        int pos = e0 + atomicAdd(&cur[p >> SRC_BITS], 1);
        csr_src[pos] = (int)(p & ((1u << SRC_BITS) - 1u));
    }
}

// ---------------- fused SAGE layer: gather-agg -> LDS -> MFMA -> LN+SiLU ------
// Block = 64 nodes. Phase A: stage own hin rows (coalesced). Phase B: each
// 16-lane group aggregates 4 nodes (fp32 register acc, 8-wide gather unroll,
// same numerics as the old aggregate kernel) and writes bf16 straight into the
// swizzled LDS stage. Phase C: MFMA from LDS (A) + global (B, L2-hot weights).
// Phase D: cross-wave LN + SiLU epilogue. No agg global round-trip.
__global__ __launch_bounds__(256) void sage_fused(
    const ushort_t* __restrict__ hprev,
    const int* __restrict__ row_ptr, const int* __restrict__ csr_src,
    const ushort_t* __restrict__ Wl, const ushort_t* __restrict__ Wr,
    const float* __restrict__ bl, const float* __restrict__ br,
    const float* __restrict__ lng, const float* __restrict__ lnb,
    ushort_t* __restrict__ hout, int n) {
    __shared__ ushort_t stage[2 * 64 * 128];   // agg half @0, hin half @8192
    __shared__ float part_s[64][4];
    __shared__ float part_s2[64][4];

    const int tid = threadIdx.x;
    const int w = tid >> 6;
    const int lane = tid & 63;
    const int quad = lane >> 4;
    const int l16 = lane & 15;
    const int n0 = blockIdx.x * 64;

    // phase A: stage own hin rows (chunk-XOR swizzle p = ch ^ (row&7))
    #pragma unroll
    for (int i = 0; i < 4; ++i) {
        int g = i * 256 + tid;
        int row = g >> 4, ch = g & 15;
        int gr = n0 + row; if (gr >= n) gr = n - 1;
        u16x8 v = *(const u16x8*)&hprev[(size_t)gr * D + ch * 8];
        *(u16x8*)&stage[8192 + row * 128 + (ch ^ (row & 7)) * 8] = v;
    }

    // phase B: aggregation. group G (=tid>>4) handles rows G*4..G*4+3
    const int G = tid >> 4;
    #pragma unroll
    for (int k = 0; k < 4; ++k) {
        int row = G * 4 + k;
        int node = n0 + row;
        float acc[8] = {0.f, 0.f, 0.f, 0.f, 0.f, 0.f, 0.f, 0.f};
        float sc = 0.0f;
        if (node < n) {
            int s0 = row_ptr[node];
            int s1 = row_ptr[node + 1];
            int e = s0;
            for (; e + 8 <= s1; e += 8) {
                int idx[8];
                #pragma unroll
                for (int j = 0; j < 8; ++j) idx[j] = csr_src[e + j];
                u16x8 vv[8];
                #pragma unroll
                for (int j = 0; j < 8; ++j)
                    vv[j] = *(const u16x8*)&hprev[(size_t)idx[j] * D + l16 * 8];
                #pragma unroll
                for (int i = 0; i < 8; ++i) {
                    float s = 0.f;
                    #pragma unroll
                    for (int j = 0; j < 8; ++j) s += bf2f(vv[j][i]);
                    acc[i] += s;
                }
            }
            for (; e < s1; ++e) {
                int src = csr_src[e];
                u16x8 vv = *(const u16x8*)&hprev[(size_t)src * D + l16 * 8];
                #pragma unroll
                for (int i = 0; i < 8; ++i) acc[i] += bf2f(vv[i]);
            }
            int dg = s1 - s0;
            sc = (dg > 0) ? (1.0f / (float)dg) : 0.0f;
        }
        u16x8 o;
        #pragma unroll
        for (int i = 0; i < 8; ++i) o[i] = f2bf(acc[i] * sc);
        *(u16x8*)&stage[row * 128 + (l16 ^ (row & 7)) * 8] = o;
    }
    __syncthreads();

    // phase C: MFMA
    f32x4 acc[4][2];
    #pragma unroll
    for (int rt = 0; rt < 4; ++rt)
        #pragma unroll
        for (int jl = 0; jl < 2; ++jl) acc[rt][jl] = (f32x4){0.f, 0.f, 0.f, 0.f};

    #pragma unroll
    for (int c = 0; c < 8; ++c) {
        const ushort_t* __restrict__ W = (c < 4) ? Wl : Wr;
        const int kb = (c & 3) * 32;
        const ushort_t* sbase = &stage[(c < 4) ? 0 : 8192];
        const int cl = (c & 3) * 4 + quad;
        bf16x8 bfr[2];
        #pragma unroll
        for (int jl = 0; jl < 2; ++jl) {
            int j = (2 * w + jl) * 16 + l16;
            bfr[jl] = *(const bf16x8*)&W[(size_t)j * D + kb + quad * 8];
        }
        bf16x8 af[4];
        #pragma unroll
        for (int rt = 0; rt < 4; ++rt) {
            int row = rt * 16 + l16;
            af[rt] = *(const bf16x8*)&sbase[row * 128 + ((cl ^ (l16 & 7)) * 8)];
        }
        #pragma unroll
        for (int rt = 0; rt < 4; ++rt)
            #pragma unroll
            for (int jl = 0; jl < 2; ++jl)
                acc[rt][jl] = __builtin_amdgcn_mfma_f32_16x16x32_bf16(af[rt], bfr[jl],
                                                                      acc[rt][jl], 0, 0, 0);
    }

    // phase D: bias + cross-wave LN + SiLU
    float bsum[2], g[2], bb[2];
    #pragma unroll
    for (int jl = 0; jl < 2; ++jl) {
        int j = (2 * w + jl) * 16 + l16;
        bsum[jl] = bl[j] + br[j];
        g[jl] = lng[j];
        bb[jl] = lnb[j];
    }
    #pragma unroll
    for (int rt = 0; rt < 4; ++rt) {
        #pragma unroll
        for (int r = 0; r < 4; ++r) {
            float v0 = acc[rt][0][r] + bsum[0];
            float v1 = acc[rt][1][r] + bsum[1];
            acc[rt][0][r] = v0;
            acc[rt][1][r] = v1;
            float s = v0 + v1;
            float s2 = v0 * v0 + v1 * v1;
            #pragma unroll
            for (int off = 1; off < 16; off <<= 1) {
                s += __shfl_xor(s, off, 64);
                s2 += __shfl_xor(s2, off, 64);
            }
            if (l16 == 0) {
                int row = rt * 16 + quad * 4 + r;
                part_s[row][w] = s;
                part_s2[row][w] = s2;
            }
        }
    }
    __syncthreads();

    ushort_t* tile = stage;
    #pragma unroll
    for (int rt = 0; rt < 4; ++rt) {
        #pragma unroll
        for (int r = 0; r < 4; ++r) {
            int row = rt * 16 + quad * 4 + r;
            float s = part_s[row][0] + part_s[row][1] + part_s[row][2] + part_s[row][3];
            float s2 = part_s2[row][0] + part_s2[row][1] + part_s2[row][2] + part_s2[row][3];
            float mean = s * (1.0f / 128.0f);
            float var = s2 * (1.0f / 128.0f) - mean * mean;
            float rstd = rsqrtf(var + LN_EPS);
            #pragma unroll
            for (int jl = 0; jl < 2; ++jl) {
                float z = (acc[rt][jl][r] - mean) * rstd * g[jl] + bb[jl];
                float sv = z / (1.0f + expf(-z));
                tile[row * 132 + (2 * w + jl) * 16 + l16] = f2bf(sv);
            }
        }
    }
    __syncthreads();
    int row = tid >> 2, seg = tid & 3;
    int node = n0 + row;
    if (node < n) {
        #pragma unroll
        for (int k2 = 0; k2 < 4; ++k2) {
            u16x8 vv = *(const u16x8*)&tile[row * 132 + seg * 32 + k2 * 8];
            *(u16x8*)&hout[(size_t)node * D + seg * 32 + k2 * 8] = vv;
        }
    }
}

// ---------------- fused MLP head: LDS-staged A + MFMA + ReLU + dot(w2) -------
__global__ __launch_bounds__(256) void mlp_head_mfma(
    const ushort_t* __restrict__ hin, const ushort_t* __restrict__ W1,
    const float* __restrict__ b1, const float* __restrict__ w2,
    const float* __restrict__ b2, float* __restrict__ out, int n) {
    __shared__ ushort_t stage[64 * 128];
    __shared__ float part[64][4];

    const int tid = threadIdx.x;
    const int w = tid >> 6;
    const int lane = tid & 63;
    const int quad = lane >> 4;
    const int l16 = lane & 15;
    const int n0 = blockIdx.x * 64;

    #pragma unroll
    for (int i = 0; i < 4; ++i) {
        int g = i * 256 + tid;
        int row = g >> 4, ch = g & 15;
        int gr = n0 + row; if (gr >= n) gr = n - 1;
        u16x8 v = *(const u16x8*)&hin[(size_t)gr * D + ch * 8];
        *(u16x8*)&stage[row * 128 + (ch ^ (row & 7)) * 8] = v;
    }
    __syncthreads();

    f32x4 acc[4][2];
    #pragma unroll
    for (int rt = 0; rt < 4; ++rt)
        #pragma unroll
        for (int jl = 0; jl < 2; ++jl) acc[rt][jl] = (f32x4){0.f, 0.f, 0.f, 0.f};

    #pragma unroll
    for (int c = 0; c < 4; ++c) {
        const int kb = c * 32;
        const int cl = c * 4 + quad;
        bf16x8 bfr[2];
        #pragma unroll
        for (int jl = 0; jl < 2; ++jl) {
            int j = (2 * w + jl) * 16 + l16;
            bfr[jl] = *(const bf16x8*)&W1[(size_t)j * D + kb + quad * 8];
        }
        bf16x8 af[4];
        #pragma unroll
        for (int rt = 0; rt < 4; ++rt) {
            int row = rt * 16 + l16;
            af[rt] = *(const bf16x8*)&stage[row * 128 + ((cl ^ (l16 & 7)) * 8)];
        }
        #pragma unroll
        for (int rt = 0; rt < 4; ++rt)
            #pragma unroll
            for (int jl = 0; jl < 2; ++jl)
                acc[rt][jl] = __builtin_amdgcn_mfma_f32_16x16x32_bf16(af[rt], bfr[jl],
                                                                      acc[rt][jl], 0, 0, 0);
    }

    float bias1[2], wv2[2];
    #pragma unroll
    for (int jl = 0; jl < 2; ++jl) {
        int j = (2 * w + jl) * 16 + l16;
        bias1[jl] = b1[j];
        wv2[jl] = w2[j];
    }
    #pragma unroll
    for (int rt = 0; rt < 4; ++rt) {
        #pragma unroll
        for (int r = 0; r < 4; ++r) {
            float p = fmaxf(acc[rt][0][r] + bias1[0], 0.0f) * wv2[0]
                    + fmaxf(acc[rt][1][r] + bias1[1], 0.0f) * wv2[1];
            #pragma unroll
            for (int off = 1; off < 16; off <<= 1) p += __shfl_xor(p, off, 64);
            if (l16 == 0) part[rt * 16 + quad * 4 + r][w] = p;
        }
    }
    __syncthreads();
    if (tid < 64) {
        int node = n0 + tid;
        if (node < n)
            out[node] = part[tid][0] + part[tid][1] + part[tid][2] + part[tid][3] + b2[0];
    }
}

// ---------------- launch ----------------
static inline size_t align_up(size_t v, size_t a) { return (v + a - 1) & ~(a - 1); }

extern "C" void kernel_launch(void* const* d_in, const int* in_sizes, int n_in,
                              void* d_out, int out_size, void* d_ws, size_t ws_size,
                              hipStream_t stream) {
    const float* x       = (const float*)d_in[0];
    const int*   ei      = (const int*)d_in[1];
    const float* lin_l_w = (const float*)d_in[2];
    const float* lin_l_b = (const float*)d_in[3];
    const float* lin_r_w = (const float*)d_in[4];
    const float* lin_r_b = (const float*)d_in[5];
    const float* ln_g    = (const float*)d_in[6];
    const float* ln_b    = (const float*)d_in[7];
    const float* mlp_w1  = (const float*)d_in[8];
    const float* mlp_b1  = (const float*)d_in[9];
    const float* mlp_w2  = (const float*)d_in[10];
    const float* mlp_b2  = (const float*)d_in[11];
    float* out = (float*)d_out;

    const int N = in_sizes[0] / D;   // 100000
    const int E = in_sizes[1] / 2;   // 1600000
    const int NB = (N + (1 << NB_SHIFT) - 1) >> NB_SHIFT;   // 782

    // workspace layout
    char* w = (char*)d_ws;
    size_t off = 0;
    int* bcnt = (int*)(w + off);       off = align_up(off + sizeof(int) * (size_t)(NB + 1), 512);
    int* bptr = (int*)(w + off);       off = align_up(off + sizeof(int) * (size_t)(NB + 1), 512);
    int* bcur = (int*)(w + off);       off = align_up(off + sizeof(int) * (size_t)(NB + 1), 512);
    int* row_ptr = (int*)(w + off);    off = align_up(off + sizeof(int) * (size_t)(N + 1), 512);
    int* csr_src = (int*)(w + off);    off = align_up(off + sizeof(int) * (size_t)E, 512);
    uint_t* pairs = (uint_t*)(w + off); off = align_up(off + sizeof(uint_t) * (size_t)E, 512);
    ushort_t* x_bf = (ushort_t*)(w + off);   off = align_up(off + 2ull * N * D, 512);
    ushort_t* h1_bf = (ushort_t*)(w + off);  off = align_up(off + 2ull * N * D, 512);
    ushort_t* h2_bf = (ushort_t*)(w + off);  off = align_up(off + 2ull * N * D, 512);
    ushort_t* wl_bf = (ushort_t*)(w + off);  off = align_up(off + 2ull * 2 * D * D, 512);
    ushort_t* wr_bf = (ushort_t*)(w + off);  off = align_up(off + 2ull * 2 * D * D, 512);
    ushort_t* w1_bf = (ushort_t*)(w + off);  off = align_up(off + 2ull * D * D, 512);

    hipMemsetAsync(bcnt, 0, sizeof(int) * (size_t)(NB + 1), stream);

    // weight + input casts (bf16)
    cast_f32_bf16<<<(2 * D * D) / (8 * 256), 256, 0, stream>>>(lin_l_w, wl_bf, 2 * D * D);
    cast_f32_bf16<<<(2 * D * D) / (8 * 256), 256, 0, stream>>>(lin_r_w, wr_bf, 2 * D * D);
    cast_f32_bf16<<<(D * D + 8 * 256 - 1) / (8 * 256), 256, 0, stream>>>(mlp_w1, w1_bf, D * D);
    cast_f32_bf16<<<(N * D) / (8 * 256), 256, 0, stream>>>(x, x_bf, N * D);

    // graph build: bucket hist -> scan -> binned packed pairs -> bucket-local CSR
    const int bin_grid = (E + BIN_CHUNK - 1) / BIN_CHUNK;
    bucket_hist_kernel<<<bin_grid, 256, 0, stream>>>(ei, E, bcnt, NB);
    scan_buckets_kernel<<<1, 1024, 0, stream>>>(bcnt, bptr, bcur, NB);
    bin_edges_kernel<<<bin_grid, 256, 0, stream>>>(ei, E, bcur, pairs, NB);
    bucket_csr_kernel<<<NB, 256, 0, stream>>>(pairs, bptr, row_ptr, csr_src, NB, N);

    const int gemm_grid = (N + 63) / 64;

    // layer 0 (aggregation fused into the GEMM)
    sage_fused<<<gemm_grid, 256, 0, stream>>>(
        x_bf, row_ptr, csr_src, wl_bf, wr_bf, lin_l_b, lin_r_b, ln_g, ln_b, h1_bf, N);
    // layer 1
    sage_fused<<<gemm_grid, 256, 0, stream>>>(
        h1_bf, row_ptr, csr_src, wl_bf + D * D, wr_bf + D * D, lin_l_b + D, lin_r_b + D,
        ln_g + D, ln_b + D, h2_bf, N);
    // head
    mlp_head_mfma<<<gemm_grid, 256, 0, stream>>>(h2_bf, w1_bf, mlp_b1, mlp_w2, mlp_b2, out, N);
}